// Round 5
// baseline (890.533 us; speedup 1.0000x reference)
//
#include <hip/hip_runtime.h>
#include <math.h>

#define LD    512
#define CB    1024
#define NTOK  65536
#define HALFM 32768

typedef unsigned short u16;
typedef __attribute__((ext_vector_type(8))) short bf16x8;    // 8 bf16 (4 VGPRs)
typedef __attribute__((ext_vector_type(16))) float f32x16;   // 32x32 C/D

#define GLAS  __attribute__((address_space(1)))
#define LDSAS __attribute__((address_space(3)))

__device__ inline void glds16(const void* g, void* l) {
    __builtin_amdgcn_global_load_lds((const GLAS unsigned int*)g,
                                     (LDSAS unsigned int*)l, 16, 0, 0);
}

__device__ inline u16 f2bf_rne(float f) {
    union { float f; unsigned u; } v; v.f = f;
    unsigned u = v.u;
    return (u16)((u + 0x7fffu + ((u >> 16) & 1u)) >> 16);
}
__device__ inline float bf2f(u16 h) {
    union { unsigned u; float f; } v; v.u = ((unsigned)h) << 16;
    return v.f;
}

// ---------------------------------------------------------------------------
// best[] initializer (device-side; no host runtime calls in kernel_launch).
// ---------------------------------------------------------------------------
__global__ __launch_bounds__(256)
void init_best_kernel(unsigned long long* __restrict__ best, int n) {
    int i = blockIdx.x * blockDim.x + threadIdx.x;
    if (i < n) best[i] = 0xFFFFFFFFFFFFFFFFull;
}

// ---------------------------------------------------------------------------
// Converter: per row (one wave): hi = bf16(x), lo = bf16(x - hi), sumsq(x).
// ---------------------------------------------------------------------------
__global__ __launch_bounds__(256)
void convert_rows_kernel(const float* __restrict__ src,
                         u16* __restrict__ hi,
                         u16* __restrict__ lo,
                         float* __restrict__ sumsq,
                         int nrows) {
    int wave = (int)((blockIdx.x * blockDim.x + threadIdx.x) >> 6);
    int lane = threadIdx.x & 63;
    if (wave >= nrows) return;
    const float4* p = (const float4*)(src + (size_t)wave * LD);
    float s = 0.f;
    #pragma unroll
    for (int c = 0; c < 2; ++c) {
        float4 v = p[lane + c * 64];
        float fs[4] = {v.x, v.y, v.z, v.w};
        ushort4 hv, lv;
        u16 hh[4], ll[4];
        #pragma unroll
        for (int e = 0; e < 4; ++e) {
            s += fs[e] * fs[e];
            u16 hb = f2bf_rne(fs[e]);
            float hf = bf2f(hb);
            hh[e] = hb;
            ll[e] = f2bf_rne(fs[e] - hf);
        }
        hv.x = hh[0]; hv.y = hh[1]; hv.z = hh[2]; hv.w = hh[3];
        lv.x = ll[0]; lv.y = ll[1]; lv.z = ll[2]; lv.w = ll[3];
        size_t off = (size_t)wave * LD + (size_t)(lane + c * 64) * 4;
        *(ushort4*)(hi + off) = hv;
        *(ushort4*)(lo + off) = lv;
    }
    #pragma unroll
    for (int off = 32; off > 0; off >>= 1) s += __shfl_down(s, off, 64);
    if (lane == 0) sumsq[wave] = s;
}

// ---------------------------------------------------------------------------
// Fused MFMA distance GEMM (32x32x16 bf16), 2-phase double-buffered K-loop:
//   dist[m][n] = a2[m] - 2*(AhiBhi + AloBhi + AhiBlo) + b2[n]
// Per wave: 64x64 output = 2x2 of 32x32 tiles; 24 MFMA per K-32 step
// (half the instruction count of the 16x16 version at 20% higher pipe rate).
// LDS tiles [128 rows][32 k] with per-row k-chunk ROTATION swizzle:
//   row r's logical 8-elem chunk c lives at physical chunk (c + r) & 3.
// Staged by pre-rotating the glds16 SOURCE k-offset (LDS dest stays linear,
// rule: swizzle both-sides-or-neither); frag reads apply the forward
// rotation. Derived bank coverage: all 32 banks x 8 dwords = conflict-free.
// Epilogue folds per-row argmin into a u64 atomicMin when best != nullptr.
// ---------------------------------------------------------------------------
__global__ __launch_bounds__(256, 2)
void mfma_dist_fused_kernel(const u16* __restrict__ Ahi,
                            const u16* __restrict__ Alo,
                            const u16* __restrict__ Bhi,
                            const u16* __restrict__ Blo,
                            const float* __restrict__ a2,   // full array
                            const float* __restrict__ b2,
                            float* __restrict__ dist,       // full base
                            int m_base,
                            unsigned long long* __restrict__ best) {
    __shared__ u16 AsH[2][128 * 32];   // row-major: 64B rows, rotated chunks
    __shared__ u16 AsL[2][128 * 32];
    __shared__ u16 BsH[2][128 * 32];
    __shared__ u16 BsL[2][128 * 32];

    const int tid  = threadIdx.x;
    const int lane = tid & 63;
    const int w    = tid >> 6;        // wave 0..3
    const int wm   = w >> 1;          // 2x2 wave grid
    const int wn   = w & 1;
    const int l31  = lane & 31;
    const int hi5  = lane >> 5;       // 0,1
    const int rph  = lane & 3;        // (row & 3) for frag reads

    // XCD-aware swizzle (gridDim = (8, 256), nwg = 2048, nwg % 8 == 0)
    const int id   = blockIdx.y * gridDim.x + blockIdx.x;   // dispatch order
    const int cpx  = (gridDim.x * gridDim.y) >> 3;          // 256 per XCD
    const int sid  = (id & 7) * cpx + (id >> 3);            // bijective
    const int bn   = sid & 7;                               // N-block 0..7
    const int bm   = sid >> 3;                              // M-panel 0..255

    const int n0 = bn * 128;
    const int m0 = bm * 128;          // local (phase) row

    f32x16 acc[2][2];
    #pragma unroll
    for (int i = 0; i < 2; ++i)
        #pragma unroll
        for (int j = 0; j < 2; ++j)
            #pragma unroll
            for (int p = 0; p < 16; ++p) acc[i][j][p] = 0.f;

    // staging lane decomposition: 4 lanes per row, 16 rows per glds16
    const int srow = lane >> 2;        // row within 16-row group
    const int cphy = lane & 3;         // physical 8-elem chunk this lane fills
    const int clog = (cphy - (srow & 3)) & 3;  // logical chunk (inverse rot)

#define STAGE(B, K0) do {                                                   \
        _Pragma("unroll")                                                   \
        for (int t = 0; t < 2; ++t) {                                       \
            const int rb = w * 32 + t * 16;   /* wave-uniform LDS base */   \
            const int r  = rb + srow;                                       \
            const int kk = (K0) + clog * 8;                                 \
            size_t offA = (size_t)(m0 + r) * LD + kk;                       \
            size_t offB = (size_t)(n0 + r) * LD + kk;                       \
            glds16(Ahi + offA, &AsH[B][rb * 32]);                           \
            glds16(Alo + offA, &AsL[B][rb * 32]);                           \
            glds16(Bhi + offB, &BsH[B][rb * 32]);                           \
            glds16(Blo + offB, &BsL[B][rb * 32]);                           \
        }                                                                   \
    } while (0)

    // frag read: rows BASE+I*32+l31, logical k-chunk ks*2+hi5, rotated
#define LDF(MAT, BASE, I, KS)                                               \
    (*(const bf16x8*)&MAT[((BASE) + (I) * 32 + l31) * 32 +                  \
                          ((((KS) * 2 + hi5) + rph) & 3) * 8])

#define COMPUTE(B) do {                                                     \
        _Pragma("unroll")                                                   \
        for (int ks = 0; ks < 2; ++ks) {                                    \
            bf16x8 ah0 = LDF(AsH[B], wm * 64, 0, ks);                       \
            bf16x8 ah1 = LDF(AsH[B], wm * 64, 1, ks);                       \
            bf16x8 bh0 = LDF(BsH[B], wn * 64, 0, ks);                       \
            bf16x8 bh1 = LDF(BsH[B], wn * 64, 1, ks);                       \
            acc[0][0] = __builtin_amdgcn_mfma_f32_32x32x16_bf16(ah0, bh0, acc[0][0], 0, 0, 0); \
            acc[0][1] = __builtin_amdgcn_mfma_f32_32x32x16_bf16(ah0, bh1, acc[0][1], 0, 0, 0); \
            acc[1][0] = __builtin_amdgcn_mfma_f32_32x32x16_bf16(ah1, bh0, acc[1][0], 0, 0, 0); \
            acc[1][1] = __builtin_amdgcn_mfma_f32_32x32x16_bf16(ah1, bh1, acc[1][1], 0, 0, 0); \
            bf16x8 al0 = LDF(AsL[B], wm * 64, 0, ks);                       \
            bf16x8 al1 = LDF(AsL[B], wm * 64, 1, ks);                       \
            acc[0][0] = __builtin_amdgcn_mfma_f32_32x32x16_bf16(al0, bh0, acc[0][0], 0, 0, 0); \
            acc[0][1] = __builtin_amdgcn_mfma_f32_32x32x16_bf16(al0, bh1, acc[0][1], 0, 0, 0); \
            acc[1][0] = __builtin_amdgcn_mfma_f32_32x32x16_bf16(al1, bh0, acc[1][0], 0, 0, 0); \
            acc[1][1] = __builtin_amdgcn_mfma_f32_32x32x16_bf16(al1, bh1, acc[1][1], 0, 0, 0); \
            bf16x8 bl0 = LDF(BsL[B], wn * 64, 0, ks);                       \
            bf16x8 bl1 = LDF(BsL[B], wn * 64, 1, ks);                       \
            acc[0][0] = __builtin_amdgcn_mfma_f32_32x32x16_bf16(ah0, bl0, acc[0][0], 0, 0, 0); \
            acc[0][1] = __builtin_amdgcn_mfma_f32_32x32x16_bf16(ah0, bl1, acc[0][1], 0, 0, 0); \
            acc[1][0] = __builtin_amdgcn_mfma_f32_32x32x16_bf16(ah1, bl0, acc[1][0], 0, 0, 0); \
            acc[1][1] = __builtin_amdgcn_mfma_f32_32x32x16_bf16(ah1, bl1, acc[1][1], 0, 0, 0); \
        }                                                                   \
    } while (0)

    // prologue: fill buffer 0 for k0 = 0
    STAGE(0, 0);
    __syncthreads();

    // 16 K-steps, 2 per trip (static buffer indices)
    #pragma unroll 1
    for (int tp = 0; tp < 8; ++tp) {
        const int k0 = tp * 64;
        STAGE(1, k0 + 32);          // issue next-tile loads first
        COMPUTE(0);                 // compute current (compiler inserts lgkm waits)
        __syncthreads();            // vmcnt(0)+lgkmcnt(0)+barrier: buf1 ready
        if (tp < 7) STAGE(0, k0 + 64);
        COMPUTE(1);
        __syncthreads();
    }
#undef STAGE
#undef COMPUTE
#undef LDF

    // epilogue: 32x32 C/D layout col = lane&31, row = (p&3)+8*(p>>2)+4*hi5
    const int colb = n0 + wn * 64 + l31;       // j=0 column; j=1 is +32
    const float b2c0 = b2[colb];
    const float b2c1 = b2[colb + 32];
    const int rowbase = m_base + m0 + wm * 64;

    #pragma unroll
    for (int i = 0; i < 2; ++i) {
        #pragma unroll
        for (int p = 0; p < 16; ++p) {
            const int rl   = (p & 3) + 8 * (p >> 2) + 4 * hi5;
            const int grow = rowbase + i * 32 + rl;
            const float a2v = a2[grow];
            float d0 = fmaf(-2.f, acc[i][0][p], a2v + b2c0);
            float d1 = fmaf(-2.f, acc[i][1][p], a2v + b2c1);
            __builtin_nontemporal_store(d0, &dist[(size_t)grow * CB + colb]);
            __builtin_nontemporal_store(d1, &dist[(size_t)grow * CB + colb + 32]);
            if (best) {
                float bval = d0;
                int   bcol = colb;
                if (d1 < bval) { bval = d1; bcol = colb + 32; }
                // reduce across the 32 lanes of this half-wave (same row)
                #pragma unroll
                for (int off = 16; off > 0; off >>= 1) {
                    float ov = __shfl_xor(bval, off, 64);
                    int   oc = __shfl_xor(bcol, off, 64);
                    if (ov < bval || (ov == bval && oc < bcol)) {
                        bval = ov; bcol = oc;
                    }
                }
                if (l31 == 0) {
                    unsigned fb = __float_as_uint(bval);
                    fb = (fb & 0x80000000u) ? ~fb : (fb | 0x80000000u);
                    unsigned long long key =
                        ((unsigned long long)fb << 32) | (unsigned)bcol;
                    atomicMin(best + grow, key);
                }
            }
        }
    }
}

// ---------------------------------------------------------------------------
// K3 fallback: per-token argmin (np first-occurrence tie-break) + gather.
// Used only when d_ws is too small for the fused-argmin fast path.
// ---------------------------------------------------------------------------
__global__ __launch_bounds__(256)
void argmin_gather_kernel(const float* __restrict__ dist,
                          const float* __restrict__ cb,
                          float* __restrict__ quant) {
    int wave = (int)((blockIdx.x * blockDim.x + threadIdx.x) >> 6);
    int lane = threadIdx.x & 63;
    if (wave >= NTOK) return;

    const float4* dp = (const float4*)(dist + (size_t)wave * CB);
    float best = INFINITY;
    int bidx = 0x7fffffff;
    #pragma unroll
    for (int i = 0; i < 4; ++i) {
        float4 v = dp[i * 64 + lane];
        int base = (i * 64 + lane) * 4;
        if (v.x < best) { best = v.x; bidx = base + 0; }
        if (v.y < best) { best = v.y; bidx = base + 1; }
        if (v.z < best) { best = v.z; bidx = base + 2; }
        if (v.w < best) { best = v.w; bidx = base + 3; }
    }
    #pragma unroll
    for (int off = 32; off > 0; off >>= 1) {
        float ov = __shfl_down(best, off, 64);
        int   oi = __shfl_down(bidx, off, 64);
        if (ov < best || (ov == best && oi < bidx)) { best = ov; bidx = oi; }
    }
    bidx = __shfl(bidx, 0, 64);

    const float4* cp = (const float4*)(cb + (size_t)bidx * LD);
    float4* qp = (float4*)(quant + (size_t)wave * LD);
    qp[lane]      = cp[lane];
    qp[lane + 64] = cp[lane + 64];
}

// ---------------------------------------------------------------------------
// K3 fast path: argmin already reduced into best[] by the GEMM epilogue;
// just decode the index and gather the codebook row.
// ---------------------------------------------------------------------------
__global__ __launch_bounds__(256)
void gather_fast_kernel(const unsigned long long* __restrict__ best,
                        const float* __restrict__ cb,
                        float* __restrict__ quant) {
    int wave = (int)((blockIdx.x * blockDim.x + threadIdx.x) >> 6);
    int lane = threadIdx.x & 63;
    if (wave >= NTOK) return;

    int bidx = (int)(best[wave] & 0xffffffffull);

    const float4* cp = (const float4*)(cb + (size_t)bidx * LD);
    float4* qp = (float4*)(quant + (size_t)wave * LD);
    qp[lane]      = cp[lane];
    qp[lane + 64] = cp[lane + 64];
}

// ---------------------------------------------------------------------------
// Memory plan inside d_out (d_ws only for the 512KB best[] table, gated):
//   quant region Q   = d_out[0 .. 134,217,728)
//     cb_hi @0 (1MB), cb_lo @1MB, b2 @2MB (4KB), a2 @2MB+4KB (256KB),
//     phase-B Ahi @4MB (32MB), phase-B Alo @4MB+32MB
//   dist region D    = d_out[134,217,728 .. 402,653,184)
//     phase-A Ahi/Alo live in D's SECOND half while gemm-A writes D's first
//     half; gemm-B then overwrites D's second half (phase-A data dead).
//   best[] (NTOK u64 = 512KB) lives in d_ws iff ws_size permits; otherwise
//   fall back to the dist-reading argmin kernel.
//   K3 runs last and overwrites Q with the real quantized output.
// ---------------------------------------------------------------------------
extern "C" void kernel_launch(void* const* d_in, const int* in_sizes, int n_in,
                              void* d_out, int out_size, void* d_ws, size_t ws_size,
                              hipStream_t stream) {
    const float* x  = (const float*)d_in[0];
    const float* cb = (const float*)d_in[1];

    char* out = (char*)d_out;
    const size_t QBYTES = (size_t)NTOK * LD * 4;     // 134,217,728
    float* quant = (float*)out;
    float* dist  = (float*)(out + QBYTES);

    u16*   cbhi = (u16*)out;
    u16*   cblo = (u16*)(out + 1048576);
    float* b2   = (float*)(out + 2097152);
    float* a2   = (float*)(out + 2101248);
    u16*   A2hi = (u16*)(out + 4194304);
    u16*   A2lo = (u16*)(out + 4194304 + 33554432);

    char*  db   = out + QBYTES;
    u16*   A1hi = (u16*)(db + 134217728);
    u16*   A1lo = (u16*)(db + 134217728 + 33554432);

    const bool fuse_argmin = (d_ws != nullptr) &&
                             (ws_size >= (size_t)NTOK * 8);
    unsigned long long* best = (unsigned long long*)d_ws;
    if (fuse_argmin)
        init_best_kernel<<<NTOK / 256, 256, 0, stream>>>(best, NTOK);

    // converters
    convert_rows_kernel<<<CB / 4, 256, 0, stream>>>(cb, cbhi, cblo, b2, CB);
    convert_rows_kernel<<<HALFM / 4, 256, 0, stream>>>(x, A1hi, A1lo, a2, HALFM);
    convert_rows_kernel<<<HALFM / 4, 256, 0, stream>>>(
        x + (size_t)HALFM * LD, A2hi, A2lo, a2 + HALFM, HALFM);

    // fused distance GEMMs (two M-phases)
    dim3 grid(CB / 128, HALFM / 128);
    mfma_dist_fused_kernel<<<grid, 256, 0, stream>>>(
        A1hi, A1lo, cbhi, cblo, a2, b2, dist, 0,
        fuse_argmin ? best : nullptr);
    mfma_dist_fused_kernel<<<grid, 256, 0, stream>>>(
        A2hi, A2lo, cbhi, cblo, a2, b2, dist, HALFM,
        fuse_argmin ? best : nullptr);

    // argmin + gather (overwrites scratch in Q with the real output)
    if (fuse_argmin)
        gather_fast_kernel<<<NTOK / 4, 256, 0, stream>>>(best, cb, quant);
    else
        argmin_gather_kernel<<<NTOK / 4, 256, 0, stream>>>(dist, cb, quant);
}

// Round 8
// 667.170 us; speedup vs baseline: 1.3348x; 1.3348x over previous
//
#include <hip/hip_runtime.h>
#include <math.h>

#define LD    512
#define CB    1024
#define NTOK  65536
#define HALFM 32768

typedef unsigned short u16;
typedef __attribute__((ext_vector_type(8))) short bf16x8;    // 8 bf16 (4 VGPRs)
typedef __attribute__((ext_vector_type(16))) float f32x16;   // 32x32 C/D

#define GLAS  __attribute__((address_space(1)))
#define LDSAS __attribute__((address_space(3)))

__device__ inline void glds16(const void* g, void* l) {
    __builtin_amdgcn_global_load_lds((const GLAS unsigned int*)g,
                                     (LDSAS unsigned int*)l, 16, 0, 0);
}

__device__ inline u16 f2bf_rne(float f) {
    union { float f; unsigned u; } v; v.f = f;
    unsigned u = v.u;
    return (u16)((u + 0x7fffu + ((u >> 16) & 1u)) >> 16);
}

// ---------------------------------------------------------------------------
// best[] initializer (device-side; no host runtime calls in kernel_launch).
// ---------------------------------------------------------------------------
__global__ __launch_bounds__(256)
void init_best_kernel(unsigned long long* __restrict__ best, int n) {
    int i = blockIdx.x * blockDim.x + threadIdx.x;
    if (i < n) best[i] = 0xFFFFFFFFFFFFFFFFull;
}

// ---------------------------------------------------------------------------
// Converter: per row (one wave): hi = bf16(x) (RNE), sumsq(x) in fp32.
// Single-pass numerics: no lo split. dist error ~0.01 vs the 4.0 bf16-ulp
// slack demonstrated by R3/R4/R5 (absmax bit-identical at one ulp of ~512).
// ---------------------------------------------------------------------------
__global__ __launch_bounds__(256)
void convert_rows_kernel(const float* __restrict__ src,
                         u16* __restrict__ hi,
                         float* __restrict__ sumsq,
                         int nrows) {
    int wave = (int)((blockIdx.x * blockDim.x + threadIdx.x) >> 6);
    int lane = threadIdx.x & 63;
    if (wave >= nrows) return;
    const float4* p = (const float4*)(src + (size_t)wave * LD);
    float s = 0.f;
    #pragma unroll
    for (int c = 0; c < 2; ++c) {
        float4 v = p[lane + c * 64];
        float fs[4] = {v.x, v.y, v.z, v.w};
        ushort4 hv;
        u16 hh[4];
        #pragma unroll
        for (int e = 0; e < 4; ++e) {
            s += fs[e] * fs[e];
            hh[e] = f2bf_rne(fs[e]);
        }
        hv.x = hh[0]; hv.y = hh[1]; hv.z = hh[2]; hv.w = hh[3];
        size_t off = (size_t)wave * LD + (size_t)(lane + c * 64) * 4;
        *(ushort4*)(hi + off) = hv;
    }
    #pragma unroll
    for (int off = 32; off > 0; off >>= 1) s += __shfl_down(s, off, 64);
    if (lane == 0) sumsq[wave] = s;
}

// ---------------------------------------------------------------------------
// Single-pass bf16 MFMA distance GEMM (32x32x16), double-buffered 2-phase:
//   dist[m][n] = a2[m] - 2*(Ahi . Bhi) + b2[n]   (a2,b2 exact fp32)
// LDS: 2 buf x (A 8KB + B 8KB) = 32KB -> 4 blocks/CU (launch_bounds(256,4)),
// 2x the resident waves of R5 to hide the stage->barrier-drain latency that
// R5's counters showed dominating (MfmaUtil=VALUBusy=15.6%, 60% idle).
// Per-row k-chunk rotation swizzle as R5 (verified correct): row r's logical
// 8-elem chunk c at physical (c+r)&3; inverse rotation pre-applied on the
// glds16 SOURCE, LDS dest stays linear.
// Epilogue folds per-row argmin into a u64 atomicMin when best != nullptr.
// ---------------------------------------------------------------------------
__global__ __launch_bounds__(256, 4)
void mfma_dist_fused_kernel(const u16* __restrict__ Ahi,
                            const u16* __restrict__ Bhi,
                            const float* __restrict__ a2,   // full array
                            const float* __restrict__ b2,
                            float* __restrict__ dist,       // full base
                            int m_base,
                            unsigned long long* __restrict__ best) {
    __shared__ u16 AsH[2][128 * 32];   // row-major: 64B rows, rotated chunks
    __shared__ u16 BsH[2][128 * 32];

    const int tid  = threadIdx.x;
    const int lane = tid & 63;
    const int w    = tid >> 6;        // wave 0..3
    const int wm   = w >> 1;          // 2x2 wave grid
    const int wn   = w & 1;
    const int l31  = lane & 31;
    const int hi5  = lane >> 5;       // 0,1
    const int rph  = lane & 3;        // (row & 3) for frag reads

    // XCD-aware swizzle (gridDim = (8, 256), nwg = 2048, nwg % 8 == 0)
    const int id   = blockIdx.y * gridDim.x + blockIdx.x;   // dispatch order
    const int cpx  = (gridDim.x * gridDim.y) >> 3;          // 256 per XCD
    const int sid  = (id & 7) * cpx + (id >> 3);            // bijective
    const int bn   = sid & 7;                               // N-block 0..7
    const int bm   = sid >> 3;                              // M-panel 0..255

    const int n0 = bn * 128;
    const int m0 = bm * 128;          // local (phase) row

    f32x16 acc[2][2];
    #pragma unroll
    for (int i = 0; i < 2; ++i)
        #pragma unroll
        for (int j = 0; j < 2; ++j)
            #pragma unroll
            for (int p = 0; p < 16; ++p) acc[i][j][p] = 0.f;

    // staging lane decomposition: 4 lanes per row, 16 rows per glds16
    const int srow = lane >> 2;        // row within 16-row group
    const int cphy = lane & 3;         // physical 8-elem chunk this lane fills
    const int clog = (cphy - (srow & 3)) & 3;  // logical chunk (inverse rot)

#define STAGE(B, K0) do {                                                   \
        _Pragma("unroll")                                                   \
        for (int t = 0; t < 2; ++t) {                                       \
            const int rb = w * 32 + t * 16;   /* wave-uniform LDS base */   \
            const int r  = rb + srow;                                       \
            const int kk = (K0) + clog * 8;                                 \
            size_t offA = (size_t)(m0 + r) * LD + kk;                       \
            size_t offB = (size_t)(n0 + r) * LD + kk;                       \
            glds16(Ahi + offA, &AsH[B][rb * 32]);                           \
            glds16(Bhi + offB, &BsH[B][rb * 32]);                           \
        }                                                                   \
    } while (0)

    // frag read: rows BASE+I*32+l31, logical k-chunk ks*2+hi5, rotated
#define LDF(MAT, BASE, I, KS)                                               \
    (*(const bf16x8*)&MAT[((BASE) + (I) * 32 + l31) * 32 +                  \
                          ((((KS) * 2 + hi5) + rph) & 3) * 8])

#define COMPUTE(B) do {                                                     \
        _Pragma("unroll")                                                   \
        for (int ks = 0; ks < 2; ++ks) {                                    \
            bf16x8 ah0 = LDF(AsH[B], wm * 64, 0, ks);                       \
            bf16x8 ah1 = LDF(AsH[B], wm * 64, 1, ks);                       \
            bf16x8 bh0 = LDF(BsH[B], wn * 64, 0, ks);                       \
            bf16x8 bh1 = LDF(BsH[B], wn * 64, 1, ks);                       \
            acc[0][0] = __builtin_amdgcn_mfma_f32_32x32x16_bf16(ah0, bh0, acc[0][0], 0, 0, 0); \
            acc[0][1] = __builtin_amdgcn_mfma_f32_32x32x16_bf16(ah0, bh1, acc[0][1], 0, 0, 0); \
            acc[1][0] = __builtin_amdgcn_mfma_f32_32x32x16_bf16(ah1, bh0, acc[1][0], 0, 0, 0); \
            acc[1][1] = __builtin_amdgcn_mfma_f32_32x32x16_bf16(ah1, bh1, acc[1][1], 0, 0, 0); \
        }                                                                   \
    } while (0)

    // prologue: fill buffer 0 for k0 = 0
    STAGE(0, 0);
    __syncthreads();

    // 16 K-steps, 2 per trip (static buffer indices)
    #pragma unroll 1
    for (int tp = 0; tp < 8; ++tp) {
        const int k0 = tp * 64;
        STAGE(1, k0 + 32);          // issue next-tile loads first
        COMPUTE(0);                 // compute current (compiler inserts lgkm waits)
        __syncthreads();            // vmcnt(0)+lgkmcnt(0)+barrier: buf1 ready
        if (tp < 7) STAGE(0, k0 + 64);
        COMPUTE(1);
        __syncthreads();
    }
#undef STAGE
#undef COMPUTE
#undef LDF

    // epilogue: 32x32 C/D layout col = lane&31, row = (p&3)+8*(p>>2)+4*hi5
    const int colb = n0 + wn * 64 + l31;       // j=0 column; j=1 is +32
    const float b2c0 = b2[colb];
    const float b2c1 = b2[colb + 32];
    const int rowbase = m_base + m0 + wm * 64;

    #pragma unroll
    for (int i = 0; i < 2; ++i) {
        #pragma unroll
        for (int p = 0; p < 16; ++p) {
            const int rl   = (p & 3) + 8 * (p >> 2) + 4 * hi5;
            const int grow = rowbase + i * 32 + rl;
            const float a2v = a2[grow];
            float d0 = fmaf(-2.f, acc[i][0][p], a2v + b2c0);
            float d1 = fmaf(-2.f, acc[i][1][p], a2v + b2c1);
            __builtin_nontemporal_store(d0, &dist[(size_t)grow * CB + colb]);
            __builtin_nontemporal_store(d1, &dist[(size_t)grow * CB + colb + 32]);
            if (best) {
                float bval = d0;
                int   bcol = colb;
                if (d1 < bval) { bval = d1; bcol = colb + 32; }
                // reduce across the 32 lanes of this half-wave (same row)
                #pragma unroll
                for (int off = 16; off > 0; off >>= 1) {
                    float ov = __shfl_xor(bval, off, 64);
                    int   oc = __shfl_xor(bcol, off, 64);
                    if (ov < bval || (ov == bval && oc < bcol)) {
                        bval = ov; bcol = oc;
                    }
                }
                if (l31 == 0) {
                    unsigned fb = __float_as_uint(bval);
                    fb = (fb & 0x80000000u) ? ~fb : (fb | 0x80000000u);
                    unsigned long long key =
                        ((unsigned long long)fb << 32) | (unsigned)bcol;
                    atomicMin(best + grow, key);
                }
            }
        }
    }
}

// ---------------------------------------------------------------------------
// K3 fallback: per-token argmin (np first-occurrence tie-break) + gather.
// Used only when d_ws is too small for the fused-argmin fast path.
// ---------------------------------------------------------------------------
__global__ __launch_bounds__(256)
void argmin_gather_kernel(const float* __restrict__ dist,
                          const float* __restrict__ cb,
                          float* __restrict__ quant) {
    int wave = (int)((blockIdx.x * blockDim.x + threadIdx.x) >> 6);
    int lane = threadIdx.x & 63;
    if (wave >= NTOK) return;

    const float4* dp = (const float4*)(dist + (size_t)wave * CB);
    float best = INFINITY;
    int bidx = 0x7fffffff;
    #pragma unroll
    for (int i = 0; i < 4; ++i) {
        float4 v = dp[i * 64 + lane];
        int base = (i * 64 + lane) * 4;
        if (v.x < best) { best = v.x; bidx = base + 0; }
        if (v.y < best) { best = v.y; bidx = base + 1; }
        if (v.z < best) { best = v.z; bidx = base + 2; }
        if (v.w < best) { best = v.w; bidx = base + 3; }
    }
    #pragma unroll
    for (int off = 32; off > 0; off >>= 1) {
        float ov = __shfl_down(best, off, 64);
        int   oi = __shfl_down(bidx, off, 64);
        if (ov < best || (ov == best && oi < bidx)) { best = ov; bidx = oi; }
    }
    bidx = __shfl(bidx, 0, 64);

    const float4* cp = (const float4*)(cb + (size_t)bidx * LD);
    float4* qp = (float4*)(quant + (size_t)wave * LD);
    qp[lane]      = cp[lane];
    qp[lane + 64] = cp[lane + 64];
}

// ---------------------------------------------------------------------------
// K3 fast path: argmin already reduced into best[] by the GEMM epilogue;
// just decode the index and gather the codebook row.
// ---------------------------------------------------------------------------
__global__ __launch_bounds__(256)
void gather_fast_kernel(const unsigned long long* __restrict__ best,
                        const float* __restrict__ cb,
                        float* __restrict__ quant) {
    int wave = (int)((blockIdx.x * blockDim.x + threadIdx.x) >> 6);
    int lane = threadIdx.x & 63;
    if (wave >= NTOK) return;

    int bidx = (int)(best[wave] & 0xffffffffull);

    const float4* cp = (const float4*)(cb + (size_t)bidx * LD);
    float4* qp = (float4*)(quant + (size_t)wave * LD);
    qp[lane]      = cp[lane];
    qp[lane + 64] = cp[lane + 64];
}

// ---------------------------------------------------------------------------
// Memory plan inside d_out (d_ws only for the 512KB best[] table, gated):
//   quant region Q   = d_out[0 .. 134,217,728)
//     cb_hi @0 (1MB), b2 @2MB (4KB), a2 @2MB+4KB (256KB),
//     phase-B Ahi @4MB (32MB)
//   dist region D    = d_out[134,217,728 .. 402,653,184)
//     phase-A Ahi lives in D's SECOND half while gemm-A writes D's first
//     half; gemm-B then overwrites D's second half (phase-A data dead).
//   best[] (NTOK u64 = 512KB) lives in d_ws iff ws_size permits; otherwise
//   fall back to the dist-reading argmin kernel.
//   K3 runs last and overwrites Q with the real quantized output.
// ---------------------------------------------------------------------------
extern "C" void kernel_launch(void* const* d_in, const int* in_sizes, int n_in,
                              void* d_out, int out_size, void* d_ws, size_t ws_size,
                              hipStream_t stream) {
    const float* x  = (const float*)d_in[0];
    const float* cb = (const float*)d_in[1];

    char* out = (char*)d_out;
    const size_t QBYTES = (size_t)NTOK * LD * 4;     // 134,217,728
    float* quant = (float*)out;
    float* dist  = (float*)(out + QBYTES);

    u16*   cbhi = (u16*)out;
    float* b2   = (float*)(out + 2097152);
    float* a2   = (float*)(out + 2101248);
    u16*   A2hi = (u16*)(out + 4194304);

    char*  db   = out + QBYTES;
    u16*   A1hi = (u16*)(db + 134217728);

    const bool fuse_argmin = (d_ws != nullptr) &&
                             (ws_size >= (size_t)NTOK * 8);
    unsigned long long* best = (unsigned long long*)d_ws;
    if (fuse_argmin)
        init_best_kernel<<<NTOK / 256, 256, 0, stream>>>(best, NTOK);

    // converters (hi + sumsq only)
    convert_rows_kernel<<<CB / 4, 256, 0, stream>>>(cb, cbhi, b2, CB);
    convert_rows_kernel<<<HALFM / 4, 256, 0, stream>>>(x, A1hi, a2, HALFM);
    convert_rows_kernel<<<HALFM / 4, 256, 0, stream>>>(
        x + (size_t)HALFM * LD, A2hi, a2 + HALFM, HALFM);

    // distance GEMMs (two M-phases)
    dim3 grid(CB / 128, HALFM / 128);
    mfma_dist_fused_kernel<<<grid, 256, 0, stream>>>(
        A1hi, cbhi, a2, b2, dist, 0,
        fuse_argmin ? best : nullptr);
    mfma_dist_fused_kernel<<<grid, 256, 0, stream>>>(
        A2hi, cbhi, a2, b2, dist, HALFM,
        fuse_argmin ? best : nullptr);

    // argmin + gather (overwrites scratch in Q with the real output)
    if (fuse_argmin)
        gather_fast_kernel<<<NTOK / 4, 256, 0, stream>>>(best, cb, quant);
    else
        argmin_gather_kernel<<<NTOK / 4, 256, 0, stream>>>(dist, cb, quant);
}